// Round 5
// baseline (226.072 us; speedup 1.0000x reference)
//
#include <hip/hip_runtime.h>
#include <hip/hip_bf16.h>

// MultiDilatelocalAttention, round 5: round 4 + transposed grid for A-tile L2
// locality (blockIdx.x = N-tile so the 9 blocks sharing an A row-tile are
// dispatched consecutively). dbuf 2-phase GEMMs, fused x fp32->f16 in QKV.

#define NTOK 50176
#define ROWQKV 1152
#define CDIM 384

typedef _Float16 half2v __attribute__((ext_vector_type(2)));
typedef _Float16 half8 __attribute__((ext_vector_type(8)));
typedef float floatx4 __attribute__((ext_vector_type(4)));

typedef __attribute__((address_space(1))) const unsigned int GU32;
typedef __attribute__((address_space(3))) unsigned int LU32;

// ---------------- fp32 -> fp16 conversion (weights only) ----------------
__global__ __launch_bounds__(256) void conv_f32_f16(const float* __restrict__ in,
                                                    _Float16* __restrict__ out, int n4) {
  int i = blockIdx.x * 256 + threadIdx.x;
  const int stride = gridDim.x * 256;
  for (; i < n4; i += stride) {
    float4 v = ((const float4*)in)[i];
    union { _Float16 h[4]; uint2 u; } o;
    o.h[0] = (_Float16)v.x; o.h[1] = (_Float16)v.y;
    o.h[2] = (_Float16)v.z; o.h[3] = (_Float16)v.w;
    ((uint2*)out)[i] = o.u;
  }
}

// ---------------- f16 MFMA GEMM, dbuf 2-phase: C[M][N] = A[M][K] * B[N][K]^T ----------------
// Grid: (N/128, M/128) — x-major dispatch makes same-A-tile blocks consecutive.
template <bool CONV_A, bool HALF_OUT>
__global__ __launch_bounds__(256) void gemm2(const void* __restrict__ Aptr,
                                             const _Float16* __restrict__ B,
                                             const float* __restrict__ bias,
                                             void* __restrict__ Cout,
                                             int N, int K) {
  __shared__ _Float16 As[2][128 * 32];
  __shared__ _Float16 Bs[2][128 * 32];
  const int tid = threadIdx.x;
  const int lane = tid & 63;
  const int wv = tid >> 6;
  const int wr = wv >> 1, wc = wv & 1;
  const size_t row0 = (size_t)blockIdx.y * 128;  // M-tile
  const int col0 = blockIdx.x * 128;             // N-tile (consecutive blocks share A)
  const int NT = K / 32;

  // --- B staging (global_load_lds, f16): 2 granules per thread ---
  const int srow = tid >> 2;                    // 0..63
  const int gslot = (tid & 3) ^ ((srow >> 1) & 3);
  const _Float16* Bbase = B + ((size_t)(col0 + srow)) * (size_t)K + gslot * 8;
  char* BsB = (char*)Bs;

  // --- A staging ---
  const int ar = tid >> 1, ah = tid & 1;
  const float* Af32 = (const float*)Aptr + (row0 + ar) * (size_t)K + ah * 16;
  const int asw0 = (ah * 2) ^ ((ar >> 1) & 3);
  const int asw1 = (ah * 2 + 1) ^ ((ar >> 1) & 3);
  const _Float16* Abase16 = (const _Float16*)Aptr + (row0 + srow) * (size_t)K + gslot * 8;
  char* AsB = (char*)As;

  float4 av[4];
  auto loadA = [&](int k0) {
    if constexpr (CONV_A) {
      av[0] = *(const float4*)(Af32 + k0);
      av[1] = *(const float4*)(Af32 + k0 + 4);
      av[2] = *(const float4*)(Af32 + k0 + 8);
      av[3] = *(const float4*)(Af32 + k0 + 12);
    }
  };
  auto loadA2 = [&](int k0, int buf) {
    if constexpr (!CONV_A) {
      __builtin_amdgcn_global_load_lds((GU32*)(Abase16 + k0),
                                       (LU32*)(AsB + buf * 8192 + tid * 16), 16, 0, 0);
      __builtin_amdgcn_global_load_lds((GU32*)(Abase16 + (size_t)64 * K + k0),
                                       (LU32*)(AsB + buf * 8192 + tid * 16 + 4096), 16, 0, 0);
    }
  };
  auto writeA = [&](int buf) {
    if constexpr (CONV_A) {
      half8 lo, hi;
      lo[0] = (_Float16)av[0].x; lo[1] = (_Float16)av[0].y;
      lo[2] = (_Float16)av[0].z; lo[3] = (_Float16)av[0].w;
      lo[4] = (_Float16)av[1].x; lo[5] = (_Float16)av[1].y;
      lo[6] = (_Float16)av[1].z; lo[7] = (_Float16)av[1].w;
      hi[0] = (_Float16)av[2].x; hi[1] = (_Float16)av[2].y;
      hi[2] = (_Float16)av[2].z; hi[3] = (_Float16)av[2].w;
      hi[4] = (_Float16)av[3].x; hi[5] = (_Float16)av[3].y;
      hi[6] = (_Float16)av[3].z; hi[7] = (_Float16)av[3].w;
      *(half8*)&As[buf][ar * 32 + asw0 * 8] = lo;
      *(half8*)&As[buf][ar * 32 + asw1 * 8] = hi;
    }
  };
  auto stageB = [&](int k0, int buf) {
    __builtin_amdgcn_global_load_lds((GU32*)(Bbase + k0),
                                     (LU32*)(BsB + buf * 8192 + tid * 16), 16, 0, 0);
    __builtin_amdgcn_global_load_lds((GU32*)(Bbase + (size_t)64 * K + k0),
                                     (LU32*)(BsB + buf * 8192 + tid * 16 + 4096), 16, 0, 0);
  };

  const int fr = lane & 15;
  const int fq = lane >> 4;
  const int rpos = (fq ^ ((fr >> 1) & 3)) * 8;

  floatx4 acc[4][4];
#pragma unroll
  for (int i = 0; i < 4; ++i)
#pragma unroll
    for (int j = 0; j < 4; ++j) acc[i][j] = (floatx4){0.f, 0.f, 0.f, 0.f};

  if constexpr (CONV_A) { loadA(0); writeA(0); } else { loadA2(0, 0); }
  stageB(0, 0);
  __syncthreads();

  int cur = 0;
  for (int t = 0; t < NT; ++t) {
    const int k1 = (t + 1) * 32;
    if (t + 1 < NT) {
      if constexpr (CONV_A) loadA(k1); else loadA2(k1, cur ^ 1);
      stageB(k1, cur ^ 1);
    }
    half8 af[4], bf[4];
#pragma unroll
    for (int f = 0; f < 4; ++f) {
      af[f] = *(const half8*)&As[cur][(wr * 64 + f * 16 + fr) * 32 + rpos];
      bf[f] = *(const half8*)&Bs[cur][(wc * 64 + f * 16 + fr) * 32 + rpos];
    }
#pragma unroll
    for (int i = 0; i < 4; ++i)
#pragma unroll
      for (int j = 0; j < 4; ++j)
        acc[i][j] = __builtin_amdgcn_mfma_f32_16x16x32_f16(af[i], bf[j], acc[i][j], 0, 0, 0);
    if (t + 1 < NT) writeA(cur ^ 1);
    __syncthreads();
    cur ^= 1;
  }

  const int crow = wr * 64 + (lane >> 4) * 4;
  const int ccol = wc * 64 + (lane & 15);
#pragma unroll
  for (int fm = 0; fm < 4; ++fm) {
#pragma unroll
    for (int fn = 0; fn < 4; ++fn) {
      const size_t r0 = (row0 + crow + fm * 16) * (size_t)N + col0 + ccol + fn * 16;
      if (HALF_OUT) {
        _Float16* C = (_Float16*)Cout;
#pragma unroll
        for (int j = 0; j < 4; ++j) C[r0 + (size_t)j * N] = (_Float16)acc[fm][fn][j];
      } else {
        float* C = (float*)Cout;
        const float bz = bias[col0 + ccol + fn * 16];
#pragma unroll
        for (int j = 0; j < 4; ++j) C[r0 + (size_t)j * N] = acc[fm][fn][j] + bz;
      }
    }
  }
}

// ---------------- Local attention: one thread per (token, head) ----------------
__global__ __launch_bounds__(256) void attn_kernel(const _Float16* __restrict__ qkv,
                                                   _Float16* __restrict__ y) {
  const int idx = blockIdx.x * 256 + threadIdx.x;  // token*12 + head
  const int head = idx % 12;
  const int token = idx / 12;
  const int branch = head >> 2;
  const int dil = branch + 1;
  const int cbase = branch * 128 + (head & 3) * 32;
  const int xx = token % 56;
  const int yy = (token / 56) % 56;
  const int bimg = token / 3136;
  const float scale = 0.17677669529663687f;  // 1/sqrt(32)

  const _Float16* qp = qkv + (size_t)token * ROWQKV + cbase;
  half2v qh[16];
  *(half8*)&qh[0] = *(const half8*)(qp);
  *(half8*)&qh[4] = *(const half8*)(qp + 8);
  *(half8*)&qh[8] = *(const half8*)(qp + 16);
  *(half8*)&qh[12] = *(const half8*)(qp + 24);

  const size_t nbase = (size_t)bimg * 3136;

  float l[9];
#pragma unroll
  for (int j = 0; j < 9; ++j) {
    const int ny = yy + (j / 3 - 1) * dil;
    const int nx = xx + (j % 3 - 1) * dil;
    float d = 0.f;
    if ((unsigned)ny < 56u && (unsigned)nx < 56u) {
      const _Float16* kp = qkv + (nbase + ny * 56 + nx) * ROWQKV + 384 + cbase;
      half2v kh[16];
      *(half8*)&kh[0] = *(const half8*)(kp);
      *(half8*)&kh[4] = *(const half8*)(kp + 8);
      *(half8*)&kh[8] = *(const half8*)(kp + 16);
      *(half8*)&kh[12] = *(const half8*)(kp + 24);
#if __has_builtin(__builtin_amdgcn_fdot2)
#pragma unroll
      for (int c = 0; c < 16; ++c) d = __builtin_amdgcn_fdot2(qh[c], kh[c], d, false);
#else
#pragma unroll
      for (int c = 0; c < 16; ++c)
        d += (float)qh[c][0] * (float)kh[c][0] + (float)qh[c][1] * (float)kh[c][1];
#endif
    }
    l[j] = d * scale;
  }

  float m = l[0];
#pragma unroll
  for (int j = 1; j < 9; ++j) m = fmaxf(m, l[j]);
  float s = 0.f;
#pragma unroll
  for (int j = 0; j < 9; ++j) { l[j] = expf(l[j] - m); s += l[j]; }
  const float rs = 1.f / s;

  float out[32];
#pragma unroll
  for (int c = 0; c < 32; ++c) out[c] = 0.f;
#pragma unroll
  for (int j = 0; j < 9; ++j) {
    const int ny = yy + (j / 3 - 1) * dil;
    const int nx = xx + (j % 3 - 1) * dil;
    if ((unsigned)ny < 56u && (unsigned)nx < 56u) {
      const _Float16* vp = qkv + (nbase + ny * 56 + nx) * ROWQKV + 768 + cbase;
      half8 vh[4];
      vh[0] = *(const half8*)(vp);
      vh[1] = *(const half8*)(vp + 8);
      vh[2] = *(const half8*)(vp + 16);
      vh[3] = *(const half8*)(vp + 24);
      const float p = l[j];
#pragma unroll
      for (int g = 0; g < 4; ++g)
#pragma unroll
        for (int e = 0; e < 8; ++e) out[g * 8 + e] = fmaf(p, (float)vh[g][e], out[g * 8 + e]);
    }
  }

  _Float16* yp = y + (size_t)token * CDIM + cbase;
  half8 oh[4];
#pragma unroll
  for (int g = 0; g < 4; ++g) {
#pragma unroll
    for (int e = 0; e < 8; ++e) oh[g][e] = (_Float16)(out[g * 8 + e] * rs);
    *(half8*)(yp + g * 8) = oh[g];
  }
}

extern "C" void kernel_launch(void* const* d_in, const int* in_sizes, int n_in,
                              void* d_out, int out_size, void* d_ws, size_t ws_size,
                              hipStream_t stream) {
  const float* x = (const float*)d_in[0];       // [16,56,56,384]
  const float* w_qkv = (const float*)d_in[1];   // [1152,384]
  const float* w_proj = (const float*)d_in[2];  // [384,384]
  const float* b_proj = (const float*)d_in[3];  // [384]
  float* out = (float*)d_out;                   // [50176,384]

  _Float16* wqh = (_Float16*)d_ws;                    // 1152*384
  _Float16* wph = wqh + (size_t)ROWQKV * CDIM;        // 384*384
  _Float16* qkvh = wph + (size_t)CDIM * CDIM;         // 50176*1152
  _Float16* yh = qkvh + (size_t)NTOK * ROWQKV;        // 50176*384

  conv_f32_f16<<<64, 256, 0, stream>>>(w_qkv, wqh, ROWQKV * CDIM / 4);
  conv_f32_f16<<<64, 256, 0, stream>>>(w_proj, wph, CDIM * CDIM / 4);

  // QKV: A = x (fp32, converted in-kernel), B = w_qkv (f16), f16 out.
  // Grid transposed: x = N-tiles (9), y = M-tiles (392).
  gemm2<true, true><<<dim3(ROWQKV / 128, NTOK / 128), 256, 0, stream>>>(
      x, wqh, nullptr, qkvh, ROWQKV, CDIM);

  attn_kernel<<<(NTOK * 12) / 256, 256, 0, stream>>>(qkvh, yh);

  // proj: A = y (f16), B = w_proj (f16), f32 out + bias. Grid (3, 392).
  gemm2<false, false><<<dim3(CDIM / 128, NTOK / 128), 256, 0, stream>>>(
      yh, wph, b_proj, out, CDIM, CDIM);
}

// Round 6
// 209.292 us; speedup vs baseline: 1.0802x; 1.0802x over previous
//
#include <hip/hip_runtime.h>
#include <hip/hip_bf16.h>

// MultiDilatelocalAttention, round 6: round 5 + XCD-chunked block remap (T1).
// 1D grid; xcd = p&7 owns a contiguous chunk of logical (m,n) tiles ordered
// n-fastest, so the 9 blocks sharing an A-tile run on the SAME XCD's L2.

#define NTOK 50176
#define ROWQKV 1152
#define CDIM 384

typedef _Float16 half2v __attribute__((ext_vector_type(2)));
typedef _Float16 half8 __attribute__((ext_vector_type(8)));
typedef float floatx4 __attribute__((ext_vector_type(4)));

typedef __attribute__((address_space(1))) const unsigned int GU32;
typedef __attribute__((address_space(3))) unsigned int LU32;

// ---------------- fp32 -> fp16 conversion (weights only) ----------------
__global__ __launch_bounds__(256) void conv_f32_f16(const float* __restrict__ in,
                                                    _Float16* __restrict__ out, int n4) {
  int i = blockIdx.x * 256 + threadIdx.x;
  const int stride = gridDim.x * 256;
  for (; i < n4; i += stride) {
    float4 v = ((const float4*)in)[i];
    union { _Float16 h[4]; uint2 u; } o;
    o.h[0] = (_Float16)v.x; o.h[1] = (_Float16)v.y;
    o.h[2] = (_Float16)v.z; o.h[3] = (_Float16)v.w;
    ((uint2*)out)[i] = o.u;
  }
}

// ---------------- f16 MFMA GEMM, dbuf 2-phase: C[M][N] = A[M][K] * B[N][K]^T ----------------
// 1D grid, XCD-chunked: p -> l = (p&7)*(nwg/8) + (p>>3); m = l/nN, n = l%nN.
template <bool CONV_A, bool HALF_OUT>
__global__ __launch_bounds__(256) void gemm2(const void* __restrict__ Aptr,
                                             const _Float16* __restrict__ B,
                                             const float* __restrict__ bias,
                                             void* __restrict__ Cout,
                                             int N, int K) {
  __shared__ _Float16 As[2][128 * 32];
  __shared__ _Float16 Bs[2][128 * 32];
  const int tid = threadIdx.x;
  const int lane = tid & 63;
  const int wv = tid >> 6;
  const int wr = wv >> 1, wc = wv & 1;

  // XCD-chunked bijective remap (nwg % 8 == 0 guaranteed by launch)
  const int nN = N >> 7;
  const int p = blockIdx.x;
  const int l = (p & 7) * (gridDim.x >> 3) + (p >> 3);
  const size_t row0 = (size_t)(l / nN) * 128;  // M-tile
  const int col0 = (l % nN) * 128;             // N-tile (n-fastest within XCD)
  const int NT = K / 32;

  // --- B staging (global_load_lds, f16): 2 granules per thread ---
  const int srow = tid >> 2;                    // 0..63
  const int gslot = (tid & 3) ^ ((srow >> 1) & 3);
  const _Float16* Bbase = B + ((size_t)(col0 + srow)) * (size_t)K + gslot * 8;
  char* BsB = (char*)Bs;

  // --- A staging ---
  const int ar = tid >> 1, ah = tid & 1;
  const float* Af32 = (const float*)Aptr + (row0 + ar) * (size_t)K + ah * 16;
  const int asw0 = (ah * 2) ^ ((ar >> 1) & 3);
  const int asw1 = (ah * 2 + 1) ^ ((ar >> 1) & 3);
  const _Float16* Abase16 = (const _Float16*)Aptr + (row0 + srow) * (size_t)K + gslot * 8;
  char* AsB = (char*)As;

  float4 av[4];
  auto loadA = [&](int k0) {
    if constexpr (CONV_A) {
      av[0] = *(const float4*)(Af32 + k0);
      av[1] = *(const float4*)(Af32 + k0 + 4);
      av[2] = *(const float4*)(Af32 + k0 + 8);
      av[3] = *(const float4*)(Af32 + k0 + 12);
    }
  };
  auto loadA2 = [&](int k0, int buf) {
    if constexpr (!CONV_A) {
      __builtin_amdgcn_global_load_lds((GU32*)(Abase16 + k0),
                                       (LU32*)(AsB + buf * 8192 + tid * 16), 16, 0, 0);
      __builtin_amdgcn_global_load_lds((GU32*)(Abase16 + (size_t)64 * K + k0),
                                       (LU32*)(AsB + buf * 8192 + tid * 16 + 4096), 16, 0, 0);
    }
  };
  auto writeA = [&](int buf) {
    if constexpr (CONV_A) {
      half8 lo, hi;
      lo[0] = (_Float16)av[0].x; lo[1] = (_Float16)av[0].y;
      lo[2] = (_Float16)av[0].z; lo[3] = (_Float16)av[0].w;
      lo[4] = (_Float16)av[1].x; lo[5] = (_Float16)av[1].y;
      lo[6] = (_Float16)av[1].z; lo[7] = (_Float16)av[1].w;
      hi[0] = (_Float16)av[2].x; hi[1] = (_Float16)av[2].y;
      hi[2] = (_Float16)av[2].z; hi[3] = (_Float16)av[2].w;
      hi[4] = (_Float16)av[3].x; hi[5] = (_Float16)av[3].y;
      hi[6] = (_Float16)av[3].z; hi[7] = (_Float16)av[3].w;
      *(half8*)&As[buf][ar * 32 + asw0 * 8] = lo;
      *(half8*)&As[buf][ar * 32 + asw1 * 8] = hi;
    }
  };
  auto stageB = [&](int k0, int buf) {
    __builtin_amdgcn_global_load_lds((GU32*)(Bbase + k0),
                                     (LU32*)(BsB + buf * 8192 + tid * 16), 16, 0, 0);
    __builtin_amdgcn_global_load_lds((GU32*)(Bbase + (size_t)64 * K + k0),
                                     (LU32*)(BsB + buf * 8192 + tid * 16 + 4096), 16, 0, 0);
  };

  const int fr = lane & 15;
  const int fq = lane >> 4;
  const int rpos = (fq ^ ((fr >> 1) & 3)) * 8;

  floatx4 acc[4][4];
#pragma unroll
  for (int i = 0; i < 4; ++i)
#pragma unroll
    for (int j = 0; j < 4; ++j) acc[i][j] = (floatx4){0.f, 0.f, 0.f, 0.f};

  if constexpr (CONV_A) { loadA(0); writeA(0); } else { loadA2(0, 0); }
  stageB(0, 0);
  __syncthreads();

  int cur = 0;
  for (int t = 0; t < NT; ++t) {
    const int k1 = (t + 1) * 32;
    if (t + 1 < NT) {
      if constexpr (CONV_A) loadA(k1); else loadA2(k1, cur ^ 1);
      stageB(k1, cur ^ 1);
    }
    half8 af[4], bf[4];
#pragma unroll
    for (int f = 0; f < 4; ++f) {
      af[f] = *(const half8*)&As[cur][(wr * 64 + f * 16 + fr) * 32 + rpos];
      bf[f] = *(const half8*)&Bs[cur][(wc * 64 + f * 16 + fr) * 32 + rpos];
    }
#pragma unroll
    for (int i = 0; i < 4; ++i)
#pragma unroll
      for (int j = 0; j < 4; ++j)
        acc[i][j] = __builtin_amdgcn_mfma_f32_16x16x32_f16(af[i], bf[j], acc[i][j], 0, 0, 0);
    if (t + 1 < NT) writeA(cur ^ 1);
    __syncthreads();
    cur ^= 1;
  }

  const int crow = wr * 64 + (lane >> 4) * 4;
  const int ccol = wc * 64 + (lane & 15);
#pragma unroll
  for (int fm = 0; fm < 4; ++fm) {
#pragma unroll
    for (int fn = 0; fn < 4; ++fn) {
      const size_t r0 = (row0 + crow + fm * 16) * (size_t)N + col0 + ccol + fn * 16;
      if (HALF_OUT) {
        _Float16* C = (_Float16*)Cout;
#pragma unroll
        for (int j = 0; j < 4; ++j) C[r0 + (size_t)j * N] = (_Float16)acc[fm][fn][j];
      } else {
        float* C = (float*)Cout;
        const float bz = bias[col0 + ccol + fn * 16];
#pragma unroll
        for (int j = 0; j < 4; ++j) C[r0 + (size_t)j * N] = acc[fm][fn][j] + bz;
      }
    }
  }
}

// ---------------- Local attention: one thread per (token, head) ----------------
__global__ __launch_bounds__(256) void attn_kernel(const _Float16* __restrict__ qkv,
                                                   _Float16* __restrict__ y) {
  const int idx = blockIdx.x * 256 + threadIdx.x;  // token*12 + head
  const int head = idx % 12;
  const int token = idx / 12;
  const int branch = head >> 2;
  const int dil = branch + 1;
  const int cbase = branch * 128 + (head & 3) * 32;
  const int xx = token % 56;
  const int yy = (token / 56) % 56;
  const int bimg = token / 3136;
  const float scale = 0.17677669529663687f;  // 1/sqrt(32)

  const _Float16* qp = qkv + (size_t)token * ROWQKV + cbase;
  half2v qh[16];
  *(half8*)&qh[0] = *(const half8*)(qp);
  *(half8*)&qh[4] = *(const half8*)(qp + 8);
  *(half8*)&qh[8] = *(const half8*)(qp + 16);
  *(half8*)&qh[12] = *(const half8*)(qp + 24);

  const size_t nbase = (size_t)bimg * 3136;

  float l[9];
#pragma unroll
  for (int j = 0; j < 9; ++j) {
    const int ny = yy + (j / 3 - 1) * dil;
    const int nx = xx + (j % 3 - 1) * dil;
    float d = 0.f;
    if ((unsigned)ny < 56u && (unsigned)nx < 56u) {
      const _Float16* kp = qkv + (nbase + ny * 56 + nx) * ROWQKV + 384 + cbase;
      half2v kh[16];
      *(half8*)&kh[0] = *(const half8*)(kp);
      *(half8*)&kh[4] = *(const half8*)(kp + 8);
      *(half8*)&kh[8] = *(const half8*)(kp + 16);
      *(half8*)&kh[12] = *(const half8*)(kp + 24);
#if __has_builtin(__builtin_amdgcn_fdot2)
#pragma unroll
      for (int c = 0; c < 16; ++c) d = __builtin_amdgcn_fdot2(qh[c], kh[c], d, false);
#else
#pragma unroll
      for (int c = 0; c < 16; ++c)
        d += (float)qh[c][0] * (float)kh[c][0] + (float)qh[c][1] * (float)kh[c][1];
#endif
    }
    l[j] = d * scale;
  }

  float m = l[0];
#pragma unroll
  for (int j = 1; j < 9; ++j) m = fmaxf(m, l[j]);
  float s = 0.f;
#pragma unroll
  for (int j = 0; j < 9; ++j) { l[j] = expf(l[j] - m); s += l[j]; }
  const float rs = 1.f / s;

  float out[32];
#pragma unroll
  for (int c = 0; c < 32; ++c) out[c] = 0.f;
#pragma unroll
  for (int j = 0; j < 9; ++j) {
    const int ny = yy + (j / 3 - 1) * dil;
    const int nx = xx + (j % 3 - 1) * dil;
    if ((unsigned)ny < 56u && (unsigned)nx < 56u) {
      const _Float16* vp = qkv + (nbase + ny * 56 + nx) * ROWQKV + 768 + cbase;
      half8 vh[4];
      vh[0] = *(const half8*)(vp);
      vh[1] = *(const half8*)(vp + 8);
      vh[2] = *(const half8*)(vp + 16);
      vh[3] = *(const half8*)(vp + 24);
      const float p = l[j];
#pragma unroll
      for (int g = 0; g < 4; ++g)
#pragma unroll
        for (int e = 0; e < 8; ++e) out[g * 8 + e] = fmaf(p, (float)vh[g][e], out[g * 8 + e]);
    }
  }

  _Float16* yp = y + (size_t)token * CDIM + cbase;
  half8 oh[4];
#pragma unroll
  for (int g = 0; g < 4; ++g) {
#pragma unroll
    for (int e = 0; e < 8; ++e) oh[g][e] = (_Float16)(out[g * 8 + e] * rs);
    *(half8*)(yp + g * 8) = oh[g];
  }
}

extern "C" void kernel_launch(void* const* d_in, const int* in_sizes, int n_in,
                              void* d_out, int out_size, void* d_ws, size_t ws_size,
                              hipStream_t stream) {
  const float* x = (const float*)d_in[0];       // [16,56,56,384]
  const float* w_qkv = (const float*)d_in[1];   // [1152,384]
  const float* w_proj = (const float*)d_in[2];  // [384,384]
  const float* b_proj = (const float*)d_in[3];  // [384]
  float* out = (float*)d_out;                   // [50176,384]

  _Float16* wqh = (_Float16*)d_ws;                    // 1152*384
  _Float16* wph = wqh + (size_t)ROWQKV * CDIM;        // 384*384
  _Float16* qkvh = wph + (size_t)CDIM * CDIM;         // 50176*1152
  _Float16* yh = qkvh + (size_t)NTOK * ROWQKV;        // 50176*384

  conv_f32_f16<<<64, 256, 0, stream>>>(w_qkv, wqh, ROWQKV * CDIM / 4);
  conv_f32_f16<<<64, 256, 0, stream>>>(w_proj, wph, CDIM * CDIM / 4);

  // QKV: A = x (fp32, converted in-kernel), B = w_qkv (f16), f16 out.
  // 1D grid 3528 = 8 * 441, XCD-chunked inside the kernel.
  gemm2<true, true><<<(NTOK / 128) * (ROWQKV / 128), 256, 0, stream>>>(
      x, wqh, nullptr, qkvh, ROWQKV, CDIM);

  attn_kernel<<<(NTOK * 12) / 256, 256, 0, stream>>>(qkvh, yh);

  // proj: A = y (f16), B = w_proj (f16), f32 out + bias. Grid 1176 = 8 * 147.
  gemm2<false, false><<<(NTOK / 128) * (CDIM / 128), 256, 0, stream>>>(
      yh, wph, b_proj, out, CDIM, CDIM);
}

// Round 7
// 187.861 us; speedup vs baseline: 1.2034x; 1.1141x over previous
//
#include <hip/hip_runtime.h>
#include <hip/hip_bf16.h>

// MultiDilatelocalAttention, round 7:
// - ONE fused fp32->f16 conversion kernel (x, w_qkv, w_proj) -> 4 launches total
// - GEMMs: round-3 global_load_lds staging (A f16) + T3-minimum double-buffer
//   (stage t+1 into buf^1, compute buf cur, one drain+barrier per K-step)
//   + XCD-chunked bijective block remap (round-6-proven FETCH fix)
// - per-(token,head) attention unchanged.

#define NTOK 50176
#define ROWQKV 1152
#define CDIM 384

typedef _Float16 half2v __attribute__((ext_vector_type(2)));
typedef _Float16 half8 __attribute__((ext_vector_type(8)));
typedef float floatx4 __attribute__((ext_vector_type(4)));

typedef __attribute__((address_space(1))) const unsigned int GU32;
typedef __attribute__((address_space(3))) unsigned int LU32;

// ---------------- fused fp32 -> fp16 conversion: x, w_qkv, w_proj ----------------
#define N_X4 (NTOK * CDIM / 4)
#define N_Q4 (ROWQKV * CDIM / 4)
#define N_P4 (CDIM * CDIM / 4)

__global__ __launch_bounds__(256) void conv_all(const float* __restrict__ x,
                                                const float* __restrict__ wq,
                                                const float* __restrict__ wp,
                                                _Float16* __restrict__ xh,
                                                _Float16* __restrict__ wqh,
                                                _Float16* __restrict__ wph) {
  const int total = N_X4 + N_Q4 + N_P4;
  int i = blockIdx.x * 256 + threadIdx.x;
  const int stride = gridDim.x * 256;
  for (; i < total; i += stride) {
    const float* src;
    _Float16* dst;
    int k;
    if (i < N_X4) { src = x; dst = xh; k = i; }
    else if (i < N_X4 + N_Q4) { src = wq; dst = wqh; k = i - N_X4; }
    else { src = wp; dst = wph; k = i - N_X4 - N_Q4; }
    float4 v = ((const float4*)src)[k];
    union { _Float16 h[4]; uint2 u; } o;
    o.h[0] = (_Float16)v.x; o.h[1] = (_Float16)v.y;
    o.h[2] = (_Float16)v.z; o.h[3] = (_Float16)v.w;
    ((uint2*)dst)[k] = o.u;
  }
}

// ---------------- f16 MFMA GEMM, T3-min dbuf: C[M][N] = A[M][K] * B[N][K]^T ----------------
// 128x128 tile, BK=32, 256 threads (4 waves 2x2), 4x4 frags of 16x16x32 per wave.
// A and B staged via global_load_lds (linear dest) with XOR-swizzled global source;
// fragment ds_reads apply the same swizzle -> 2-way max bank aliasing (free).
// 1D grid, XCD-chunked remap: l = (p&7)*(nwg/8) + (p>>3); m = l/nN, n = l%nN.
template <bool HALF_OUT>
__global__ __launch_bounds__(256) void gemm3(const _Float16* __restrict__ A,
                                             const _Float16* __restrict__ B,
                                             const float* __restrict__ bias,
                                             void* __restrict__ Cout,
                                             int N, int K) {
  __shared__ _Float16 As[2][128 * 32];
  __shared__ _Float16 Bs[2][128 * 32];
  const int tid = threadIdx.x;
  const int lane = tid & 63;
  const int wv = tid >> 6;
  const int wr = wv >> 1, wc = wv & 1;

  const int nN = N >> 7;
  const int p = blockIdx.x;
  const int l = (p & 7) * (gridDim.x >> 3) + (p >> 3);
  const size_t row0 = (size_t)(l / nN) * 128;
  const int col0 = (l % nN) * 128;
  const int NT = K / 32;

  // staging: thread -> 16B granule (srow = tid>>2, slot = tid&3), two row-halves
  const int srow = tid >> 2;
  const int gslot = (tid & 3) ^ ((srow >> 1) & 3);  // swizzled source slot
  const _Float16* Abase = A + (row0 + srow) * (size_t)K + gslot * 8;
  const _Float16* Bbase = B + ((size_t)(col0 + srow)) * (size_t)K + gslot * 8;
  char* AsB = (char*)As;
  char* BsB = (char*)Bs;

  auto stage = [&](int k0, int buf) {
    __builtin_amdgcn_global_load_lds((GU32*)(Abase + k0),
                                     (LU32*)(AsB + buf * 8192 + tid * 16), 16, 0, 0);
    __builtin_amdgcn_global_load_lds((GU32*)(Abase + (size_t)64 * K + k0),
                                     (LU32*)(AsB + buf * 8192 + tid * 16 + 4096), 16, 0, 0);
    __builtin_amdgcn_global_load_lds((GU32*)(Bbase + k0),
                                     (LU32*)(BsB + buf * 8192 + tid * 16), 16, 0, 0);
    __builtin_amdgcn_global_load_lds((GU32*)(Bbase + (size_t)64 * K + k0),
                                     (LU32*)(BsB + buf * 8192 + tid * 16 + 4096), 16, 0, 0);
  };

  // fragment read addressing (same swizzle)
  const int fr = lane & 15;
  const int fq = lane >> 4;
  const int rpos = (fq ^ ((fr >> 1) & 3)) * 8;

  floatx4 acc[4][4];
#pragma unroll
  for (int i = 0; i < 4; ++i)
#pragma unroll
    for (int j = 0; j < 4; ++j) acc[i][j] = (floatx4){0.f, 0.f, 0.f, 0.f};

  stage(0, 0);
  __syncthreads();

  int cur = 0;
  for (int t = 0; t < NT; ++t) {
    if (t + 1 < NT) stage((t + 1) * 32, cur ^ 1);  // loads get full compute window
    half8 af[4], bf[4];
#pragma unroll
    for (int f = 0; f < 4; ++f) {
      af[f] = *(const half8*)&As[cur][(wr * 64 + f * 16 + fr) * 32 + rpos];
      bf[f] = *(const half8*)&Bs[cur][(wc * 64 + f * 16 + fr) * 32 + rpos];
    }
#pragma unroll
    for (int i = 0; i < 4; ++i)
#pragma unroll
      for (int j = 0; j < 4; ++j)
        acc[i][j] = __builtin_amdgcn_mfma_f32_16x16x32_f16(af[i], bf[j], acc[i][j], 0, 0, 0);
    __syncthreads();  // drains t+1 stage (vmcnt0) after the MFMA window
    cur ^= 1;
  }

  // epilogue: C/D layout col=lane&15, row=(lane>>4)*4+reg
  const int crow = wr * 64 + (lane >> 4) * 4;
  const int ccol = wc * 64 + (lane & 15);
#pragma unroll
  for (int fm = 0; fm < 4; ++fm) {
#pragma unroll
    for (int fn = 0; fn < 4; ++fn) {
      const size_t r0 = (row0 + crow + fm * 16) * (size_t)N + col0 + ccol + fn * 16;
      if (HALF_OUT) {
        _Float16* C = (_Float16*)Cout;
#pragma unroll
        for (int j = 0; j < 4; ++j) C[r0 + (size_t)j * N] = (_Float16)acc[fm][fn][j];
      } else {
        float* C = (float*)Cout;
        const float bz = bias[col0 + ccol + fn * 16];
#pragma unroll
        for (int j = 0; j < 4; ++j) C[r0 + (size_t)j * N] = acc[fm][fn][j] + bz;
      }
    }
  }
}

// ---------------- Local attention: one thread per (token, head) ----------------
__global__ __launch_bounds__(256) void attn_kernel(const _Float16* __restrict__ qkv,
                                                   _Float16* __restrict__ y) {
  const int idx = blockIdx.x * 256 + threadIdx.x;  // token*12 + head
  const int head = idx % 12;
  const int token = idx / 12;
  const int branch = head >> 2;
  const int dil = branch + 1;
  const int cbase = branch * 128 + (head & 3) * 32;
  const int xx = token % 56;
  const int yy = (token / 56) % 56;
  const int bimg = token / 3136;
  const float scale = 0.17677669529663687f;  // 1/sqrt(32)

  const _Float16* qp = qkv + (size_t)token * ROWQKV + cbase;
  half2v qh[16];
  *(half8*)&qh[0] = *(const half8*)(qp);
  *(half8*)&qh[4] = *(const half8*)(qp + 8);
  *(half8*)&qh[8] = *(const half8*)(qp + 16);
  *(half8*)&qh[12] = *(const half8*)(qp + 24);

  const size_t nbase = (size_t)bimg * 3136;

  float l[9];
#pragma unroll
  for (int j = 0; j < 9; ++j) {
    const int ny = yy + (j / 3 - 1) * dil;
    const int nx = xx + (j % 3 - 1) * dil;
    float d = 0.f;
    if ((unsigned)ny < 56u && (unsigned)nx < 56u) {
      const _Float16* kp = qkv + (nbase + ny * 56 + nx) * ROWQKV + 384 + cbase;
      half2v kh[16];
      *(half8*)&kh[0] = *(const half8*)(kp);
      *(half8*)&kh[4] = *(const half8*)(kp + 8);
      *(half8*)&kh[8] = *(const half8*)(kp + 16);
      *(half8*)&kh[12] = *(const half8*)(kp + 24);
#if __has_builtin(__builtin_amdgcn_fdot2)
#pragma unroll
      for (int c = 0; c < 16; ++c) d = __builtin_amdgcn_fdot2(qh[c], kh[c], d, false);
#else
#pragma unroll
      for (int c = 0; c < 16; ++c)
        d += (float)qh[c][0] * (float)kh[c][0] + (float)qh[c][1] * (float)kh[c][1];
#endif
    }
    l[j] = d * scale;
  }

  float m = l[0];
#pragma unroll
  for (int j = 1; j < 9; ++j) m = fmaxf(m, l[j]);
  float s = 0.f;
#pragma unroll
  for (int j = 0; j < 9; ++j) { l[j] = expf(l[j] - m); s += l[j]; }
  const float rs = 1.f / s;

  float out[32];
#pragma unroll
  for (int c = 0; c < 32; ++c) out[c] = 0.f;
#pragma unroll
  for (int j = 0; j < 9; ++j) {
    const int ny = yy + (j / 3 - 1) * dil;
    const int nx = xx + (j % 3 - 1) * dil;
    if ((unsigned)ny < 56u && (unsigned)nx < 56u) {
      const _Float16* vp = qkv + (nbase + ny * 56 + nx) * ROWQKV + 768 + cbase;
      half8 vh[4];
      vh[0] = *(const half8*)(vp);
      vh[1] = *(const half8*)(vp + 8);
      vh[2] = *(const half8*)(vp + 16);
      vh[3] = *(const half8*)(vp + 24);
      const float p = l[j];
#pragma unroll
      for (int g = 0; g < 4; ++g)
#pragma unroll
        for (int e = 0; e < 8; ++e) out[g * 8 + e] = fmaf(p, (float)vh[g][e], out[g * 8 + e]);
    }
  }

  _Float16* yp = y + (size_t)token * CDIM + cbase;
  half8 oh[4];
#pragma unroll
  for (int g = 0; g < 4; ++g) {
#pragma unroll
    for (int e = 0; e < 8; ++e) oh[g][e] = (_Float16)(out[g * 8 + e] * rs);
    *(half8*)(yp + g * 8) = oh[g];
  }
}

extern "C" void kernel_launch(void* const* d_in, const int* in_sizes, int n_in,
                              void* d_out, int out_size, void* d_ws, size_t ws_size,
                              hipStream_t stream) {
  const float* x = (const float*)d_in[0];       // [16,56,56,384]
  const float* w_qkv = (const float*)d_in[1];   // [1152,384]
  const float* w_proj = (const float*)d_in[2];  // [384,384]
  const float* b_proj = (const float*)d_in[3];  // [384]
  float* out = (float*)d_out;                   // [50176,384]

  _Float16* xh = (_Float16*)d_ws;                     // 50176*384
  _Float16* wqh = xh + (size_t)NTOK * CDIM;           // 1152*384
  _Float16* wph = wqh + (size_t)ROWQKV * CDIM;        // 384*384
  _Float16* qkvh = wph + (size_t)CDIM * CDIM;         // 50176*1152
  _Float16* yh = qkvh + (size_t)NTOK * ROWQKV;        // 50176*384

  // 1) all conversions in one launch
  conv_all<<<2048, 256, 0, stream>>>(x, w_qkv, w_proj, xh, wqh, wph);

  // 2) QKV GEMM: 1D grid 3528 = 8*441, XCD-chunked
  gemm3<true><<<(NTOK / 128) * (ROWQKV / 128), 256, 0, stream>>>(
      xh, wqh, nullptr, qkvh, ROWQKV, CDIM);

  // 3) multi-dilation local attention
  attn_kernel<<<(NTOK * 12) / 256, 256, 0, stream>>>(qkvh, yh);

  // 4) proj GEMM: 1D grid 1176 = 8*147, XCD-chunked, f32 out + bias
  gemm3<false><<<(NTOK / 128) * (CDIM / 128), 256, 0, stream>>>(
      yh, wph, b_proj, out, CDIM, CDIM);
}

// Round 8
// 183.281 us; speedup vs baseline: 1.2335x; 1.0250x over previous
//
#include <hip/hip_runtime.h>
#include <hip/hip_bf16.h>

// MultiDilatelocalAttention, round 8: round 7 + counted-vmcnt raw-barrier
// pipeline in the GEMMs (T4: stage(t+1)'s loads stay in flight across the
// MFMA window; vmcnt(4) waits only the previous tile's 4 loads; no vmcnt(0)
// drain in the main loop). Everything else unchanged from round 7.

#define NTOK 50176
#define ROWQKV 1152
#define CDIM 384

typedef _Float16 half2v __attribute__((ext_vector_type(2)));
typedef _Float16 half8 __attribute__((ext_vector_type(8)));
typedef float floatx4 __attribute__((ext_vector_type(4)));

typedef __attribute__((address_space(1))) const unsigned int GU32;
typedef __attribute__((address_space(3))) unsigned int LU32;

// ---------------- fused fp32 -> fp16 conversion: x, w_qkv, w_proj ----------------
#define N_X4 (NTOK * CDIM / 4)
#define N_Q4 (ROWQKV * CDIM / 4)
#define N_P4 (CDIM * CDIM / 4)

__global__ __launch_bounds__(256) void conv_all(const float* __restrict__ x,
                                                const float* __restrict__ wq,
                                                const float* __restrict__ wp,
                                                _Float16* __restrict__ xh,
                                                _Float16* __restrict__ wqh,
                                                _Float16* __restrict__ wph) {
  const int total = N_X4 + N_Q4 + N_P4;
  int i = blockIdx.x * 256 + threadIdx.x;
  const int stride = gridDim.x * 256;
  for (; i < total; i += stride) {
    const float* src;
    _Float16* dst;
    int k;
    if (i < N_X4) { src = x; dst = xh; k = i; }
    else if (i < N_X4 + N_Q4) { src = wq; dst = wqh; k = i - N_X4; }
    else { src = wp; dst = wph; k = i - N_X4 - N_Q4; }
    float4 v = ((const float4*)src)[k];
    union { _Float16 h[4]; uint2 u; } o;
    o.h[0] = (_Float16)v.x; o.h[1] = (_Float16)v.y;
    o.h[2] = (_Float16)v.z; o.h[3] = (_Float16)v.w;
    ((uint2*)dst)[k] = o.u;
  }
}

// ---------------- f16 MFMA GEMM, counted-vmcnt dbuf: C = A * B^T ----------------
// 128x128 tile, BK=32, 256 threads (4 waves 2x2), 4x4 frags of 16x16x32 per wave.
// Raw s_barrier; vmcnt(4) before compute (waits ONLY the previous tile's 4
// global_load_lds per thread; the 4 just-issued loads stay in flight).
// 1D grid, XCD-chunked remap.
template <bool HALF_OUT>
__global__ __launch_bounds__(256) void gemm3(const _Float16* __restrict__ A,
                                             const _Float16* __restrict__ B,
                                             const float* __restrict__ bias,
                                             void* __restrict__ Cout,
                                             int N, int K) {
  __shared__ _Float16 As[2][128 * 32];
  __shared__ _Float16 Bs[2][128 * 32];
  const int tid = threadIdx.x;
  const int lane = tid & 63;
  const int wv = tid >> 6;
  const int wr = wv >> 1, wc = wv & 1;

  const int nN = N >> 7;
  const int p = blockIdx.x;
  const int l = (p & 7) * (gridDim.x >> 3) + (p >> 3);
  const size_t row0 = (size_t)(l / nN) * 128;
  const int col0 = (l % nN) * 128;
  const int NT = K / 32;

  const int srow = tid >> 2;
  const int gslot = (tid & 3) ^ ((srow >> 1) & 3);  // swizzled source slot
  const _Float16* Abase = A + (row0 + srow) * (size_t)K + gslot * 8;
  const _Float16* Bbase = B + ((size_t)(col0 + srow)) * (size_t)K + gslot * 8;
  char* AsB = (char*)As;
  char* BsB = (char*)Bs;

  auto stage = [&](int k0, int buf) {
    __builtin_amdgcn_global_load_lds((GU32*)(Abase + k0),
                                     (LU32*)(AsB + buf * 8192 + tid * 16), 16, 0, 0);
    __builtin_amdgcn_global_load_lds((GU32*)(Abase + (size_t)64 * K + k0),
                                     (LU32*)(AsB + buf * 8192 + tid * 16 + 4096), 16, 0, 0);
    __builtin_amdgcn_global_load_lds((GU32*)(Bbase + k0),
                                     (LU32*)(BsB + buf * 8192 + tid * 16), 16, 0, 0);
    __builtin_amdgcn_global_load_lds((GU32*)(Bbase + (size_t)64 * K + k0),
                                     (LU32*)(BsB + buf * 8192 + tid * 16 + 4096), 16, 0, 0);
  };

  const int fr = lane & 15;
  const int fq = lane >> 4;
  const int rpos = (fq ^ ((fr >> 1) & 3)) * 8;

  floatx4 acc[4][4];
#pragma unroll
  for (int i = 0; i < 4; ++i)
#pragma unroll
    for (int j = 0; j < 4; ++j) acc[i][j] = (floatx4){0.f, 0.f, 0.f, 0.f};

  // prologue: tile 0 staged and fully drained
  stage(0, 0);
  asm volatile("s_waitcnt vmcnt(0)" ::: "memory");
  __builtin_amdgcn_s_barrier();

  int cur = 0;
  for (int t = 0; t < NT; ++t) {
    if (t + 1 < NT) {
      stage((t + 1) * 32, cur ^ 1);  // 4 loads issued; stay in flight over MFMA
      asm volatile("s_waitcnt vmcnt(4)" ::: "memory");  // wait ONLY tile-t loads
    } else {
      asm volatile("s_waitcnt vmcnt(0)" ::: "memory");
    }
    __builtin_amdgcn_s_barrier();          // all threads' tile-t loads landed
    __builtin_amdgcn_sched_barrier(0);     // fence: no hoisting across the wait
    half8 af[4], bf[4];
#pragma unroll
    for (int f = 0; f < 4; ++f) {
      af[f] = *(const half8*)&As[cur][(wr * 64 + f * 16 + fr) * 32 + rpos];
      bf[f] = *(const half8*)&Bs[cur][(wc * 64 + f * 16 + fr) * 32 + rpos];
    }
#pragma unroll
    for (int i = 0; i < 4; ++i)
#pragma unroll
      for (int j = 0; j < 4; ++j)
        acc[i][j] = __builtin_amdgcn_mfma_f32_16x16x32_f16(af[i], bf[j], acc[i][j], 0, 0, 0);
    __builtin_amdgcn_sched_barrier(0);     // keep ds_reads above the barrier
    __builtin_amdgcn_s_barrier();          // reads of buf cur done -> next stage may overwrite
    cur ^= 1;
  }

  const int crow = wr * 64 + (lane >> 4) * 4;
  const int ccol = wc * 64 + (lane & 15);
#pragma unroll
  for (int fm = 0; fm < 4; ++fm) {
#pragma unroll
    for (int fn = 0; fn < 4; ++fn) {
      const size_t r0 = (row0 + crow + fm * 16) * (size_t)N + col0 + ccol + fn * 16;
      if (HALF_OUT) {
        _Float16* C = (_Float16*)Cout;
#pragma unroll
        for (int j = 0; j < 4; ++j) C[r0 + (size_t)j * N] = (_Float16)acc[fm][fn][j];
      } else {
        float* C = (float*)Cout;
        const float bz = bias[col0 + ccol + fn * 16];
#pragma unroll
        for (int j = 0; j < 4; ++j) C[r0 + (size_t)j * N] = acc[fm][fn][j] + bz;
      }
    }
  }
}

// ---------------- Local attention: one thread per (token, head) ----------------
__global__ __launch_bounds__(256) void attn_kernel(const _Float16* __restrict__ qkv,
                                                   _Float16* __restrict__ y) {
  const int idx = blockIdx.x * 256 + threadIdx.x;  // token*12 + head
  const int head = idx % 12;
  const int token = idx / 12;
  const int branch = head >> 2;
  const int dil = branch + 1;
  const int cbase = branch * 128 + (head & 3) * 32;
  const int xx = token % 56;
  const int yy = (token / 56) % 56;
  const int bimg = token / 3136;
  const float scale = 0.17677669529663687f;  // 1/sqrt(32)

  const _Float16* qp = qkv + (size_t)token * ROWQKV + cbase;
  half2v qh[16];
  *(half8*)&qh[0] = *(const half8*)(qp);
  *(half8*)&qh[4] = *(const half8*)(qp + 8);
  *(half8*)&qh[8] = *(const half8*)(qp + 16);
  *(half8*)&qh[12] = *(const half8*)(qp + 24);

  const size_t nbase = (size_t)bimg * 3136;

  float l[9];
#pragma unroll
  for (int j = 0; j < 9; ++j) {
    const int ny = yy + (j / 3 - 1) * dil;
    const int nx = xx + (j % 3 - 1) * dil;
    float d = 0.f;
    if ((unsigned)ny < 56u && (unsigned)nx < 56u) {
      const _Float16* kp = qkv + (nbase + ny * 56 + nx) * ROWQKV + 384 + cbase;
      half2v kh[16];
      *(half8*)&kh[0] = *(const half8*)(kp);
      *(half8*)&kh[4] = *(const half8*)(kp + 8);
      *(half8*)&kh[8] = *(const half8*)(kp + 16);
      *(half8*)&kh[12] = *(const half8*)(kp + 24);
#if __has_builtin(__builtin_amdgcn_fdot2)
#pragma unroll
      for (int c = 0; c < 16; ++c) d = __builtin_amdgcn_fdot2(qh[c], kh[c], d, false);
#else
#pragma unroll
      for (int c = 0; c < 16; ++c)
        d += (float)qh[c][0] * (float)kh[c][0] + (float)qh[c][1] * (float)kh[c][1];
#endif
    }
    l[j] = d * scale;
  }

  float m = l[0];
#pragma unroll
  for (int j = 1; j < 9; ++j) m = fmaxf(m, l[j]);
  float s = 0.f;
#pragma unroll
  for (int j = 0; j < 9; ++j) { l[j] = expf(l[j] - m); s += l[j]; }
  const float rs = 1.f / s;

  float out[32];
#pragma unroll
  for (int c = 0; c < 32; ++c) out[c] = 0.f;
#pragma unroll
  for (int j = 0; j < 9; ++j) {
    const int ny = yy + (j / 3 - 1) * dil;
    const int nx = xx + (j % 3 - 1) * dil;
    if ((unsigned)ny < 56u && (unsigned)nx < 56u) {
      const _Float16* vp = qkv + (nbase + ny * 56 + nx) * ROWQKV + 768 + cbase;
      half8 vh[4];
      vh[0] = *(const half8*)(vp);
      vh[1] = *(const half8*)(vp + 8);
      vh[2] = *(const half8*)(vp + 16);
      vh[3] = *(const half8*)(vp + 24);
      const float p = l[j];
#pragma unroll
      for (int g = 0; g < 4; ++g)
#pragma unroll
        for (int e = 0; e < 8; ++e) out[g * 8 + e] = fmaf(p, (float)vh[g][e], out[g * 8 + e]);
    }
  }

  _Float16* yp = y + (size_t)token * CDIM + cbase;
  half8 oh[4];
#pragma unroll
  for (int g = 0; g < 4; ++g) {
#pragma unroll
    for (int e = 0; e < 8; ++e) oh[g][e] = (_Float16)(out[g * 8 + e] * rs);
    *(half8*)(yp + g * 8) = oh[g];
  }
}

extern "C" void kernel_launch(void* const* d_in, const int* in_sizes, int n_in,
                              void* d_out, int out_size, void* d_ws, size_t ws_size,
                              hipStream_t stream) {
  const float* x = (const float*)d_in[0];       // [16,56,56,384]
  const float* w_qkv = (const float*)d_in[1];   // [1152,384]
  const float* w_proj = (const float*)d_in[2];  // [384,384]
  const float* b_proj = (const float*)d_in[3];  // [384]
  float* out = (float*)d_out;                   // [50176,384]

  _Float16* xh = (_Float16*)d_ws;                     // 50176*384
  _Float16* wqh = xh + (size_t)NTOK * CDIM;           // 1152*384
  _Float16* wph = wqh + (size_t)ROWQKV * CDIM;        // 384*384
  _Float16* qkvh = wph + (size_t)CDIM * CDIM;         // 50176*1152
  _Float16* yh = qkvh + (size_t)NTOK * ROWQKV;        // 50176*384

  conv_all<<<2048, 256, 0, stream>>>(x, w_qkv, w_proj, xh, wqh, wph);

  gemm3<true><<<(NTOK / 128) * (ROWQKV / 128), 256, 0, stream>>>(
      xh, wqh, nullptr, qkvh, ROWQKV, CDIM);

  attn_kernel<<<(NTOK * 12) / 256, 256, 0, stream>>>(qkvh, yh);

  gemm3<false><<<(NTOK / 128) * (CDIM / 128), 256, 0, stream>>>(
      yh, wph, b_proj, out, CDIM, CDIM);
}